// Round 2
// baseline (2903.901 us; speedup 1.0000x reference)
//
#include <hip/hip_runtime.h>
#include <hip/hip_bf16.h>
#include <math.h>

#define T_TOK 8192
#define M_MEM 4096
#define DKV 64
#define SCALE 0.125f
#define CCH 256
#define NCH (T_TOK / CCH)   // 32

__device__ __forceinline__ float4 f4z() { return make_float4(0.f, 0.f, 0.f, 0.f); }
__device__ __forceinline__ float4 f4fma(float s, const float4 a, float4 c) {
    c.x = fmaf(s, a.x, c.x); c.y = fmaf(s, a.y, c.y);
    c.z = fmaf(s, a.z, c.z); c.w = fmaf(s, a.w, c.w); return c;
}
__device__ __forceinline__ float4 f4scale(const float4 a, float s) {
    return make_float4(a.x * s, a.y * s, a.z * s, a.w * s);
}
__device__ __forceinline__ float4 f4sub(const float4 a, const float4 b) {
    return make_float4(a.x - b.x, a.y - b.y, a.z - b.z, a.w - b.w);
}
__device__ __forceinline__ float4 f4exp(const float4 s, float mf, float sc) {
    return make_float4(__expf(s.x - mf) * sc, __expf(s.y - mf) * sc,
                       __expf(s.z - mf) * sc, __expf(s.w - mf) * sc);
}
__device__ __forceinline__ float dot4(const float4 a, const float4 b) {
    return a.x * b.x + a.y * b.y + a.z * b.z + a.w * b.w;
}

// ---------------------------------------------------------------------------
// K1: online softmax stats + a_x@V accumulation. NO logit materialization.
// side 0: k-side -> mfk, rsk, d = a_k@V - v.  side 1: q-side -> mfq, rsq,
// rq = a_q@V written directly to out. grid (T/32, 2), 256 threads.
// row = tid>>3 (32 rows/block), sub = tid&7 (8 lanes per row).
// ---------------------------------------------------------------------------
__global__ __launch_bounds__(256) void k1_stats(
    const float* __restrict__ kin, const float* __restrict__ qin,
    const float* __restrict__ Km, const float* __restrict__ Vm,
    const float* __restrict__ vin,
    float* __restrict__ mfk, float* __restrict__ rsk,
    float* __restrict__ mfq, float* __restrict__ rsq,
    float* __restrict__ db, float* __restrict__ out)
{
    __shared__ float KtT[64][64];   // [kk][m] transposed K tile
    __shared__ float Vt[64][68];    // [m][dv]
    __shared__ float pl[32][65];    // [row][m] exchange buffer

    const int tid = threadIdx.x;
    const int row = tid >> 3, sub = tid & 7;
    const int side = blockIdx.y;
    const int grow = blockIdx.x * 32 + row;
    const float* src = (side ? qin : kin);

    float4 kr4[16];
    {
        const float4* sr = (const float4*)(src + (size_t)grow * 64);
        #pragma unroll
        for (int i = 0; i < 16; i++) kr4[i] = f4scale(sr[i], SCALE);
    }

    float mrun = -INFINITY, srun = 0.f;
    float4 daccA = f4z(), daccB = f4z();

    for (int mt = 0; mt < 64; mt++) {
        {   // stage K tile (transposed) and V tile
            const int m = tid & 63;
            const int q0 = tid >> 6;
            #pragma unroll
            for (int q = 0; q < 4; q++) {
                int kk4 = q0 + q * 4;
                float4 f = *(const float4*)(Km + (size_t)(mt * 64 + m) * 64 + kk4 * 4);
                KtT[kk4 * 4 + 0][m] = f.x; KtT[kk4 * 4 + 1][m] = f.y;
                KtT[kk4 * 4 + 2][m] = f.z; KtT[kk4 * 4 + 3][m] = f.w;
            }
            const int m2 = tid >> 2;
            #pragma unroll
            for (int q = 0; q < 4; q++) {
                int c4 = (tid & 3) + q * 4;
                *(float4*)&Vt[m2][c4 * 4] =
                    *(const float4*)(Vm + (size_t)(mt * 64 + m2) * 64 + c4 * 4);
            }
        }
        __syncthreads();

        float4 sA = f4z(), sB = f4z();
        #pragma unroll
        for (int kk4 = 0; kk4 < 16; kk4++) {
            float4 kf = kr4[kk4];
            #pragma unroll
            for (int c = 0; c < 4; c++) {
                int kk = kk4 * 4 + c;
                float kv = (c == 0 ? kf.x : c == 1 ? kf.y : c == 2 ? kf.z : kf.w);
                float4 a = *(const float4*)&KtT[kk][sub * 8];
                float4 b = *(const float4*)&KtT[kk][sub * 8 + 4];
                sA = f4fma(kv, a, sA); sB = f4fma(kv, b, sB);
            }
        }
        float tmax = fmaxf(fmaxf(fmaxf(sA.x, sA.y), fmaxf(sA.z, sA.w)),
                           fmaxf(fmaxf(sB.x, sB.y), fmaxf(sB.z, sB.w)));
        #pragma unroll
        for (int o = 1; o < 8; o <<= 1) tmax = fmaxf(tmax, __shfl_xor(tmax, o, 8));
        float mnew = fmaxf(mrun, tmax);
        float corr = __expf(mrun - mnew);
        float4 pA = f4exp(sA, mnew, 1.f), pB = f4exp(sB, mnew, 1.f);
        float ts = pA.x + pA.y + pA.z + pA.w + pB.x + pB.y + pB.z + pB.w;
        #pragma unroll
        for (int o = 1; o < 8; o <<= 1) ts += __shfl_xor(ts, o, 8);
        srun = srun * corr + ts;
        mrun = mnew;
        daccA = f4scale(daccA, corr); daccB = f4scale(daccB, corr);
        pl[row][sub * 8 + 0] = pA.x; pl[row][sub * 8 + 1] = pA.y;
        pl[row][sub * 8 + 2] = pA.z; pl[row][sub * 8 + 3] = pA.w;
        pl[row][sub * 8 + 4] = pB.x; pl[row][sub * 8 + 5] = pB.y;
        pl[row][sub * 8 + 6] = pB.z; pl[row][sub * 8 + 7] = pB.w;
        __syncthreads();

        #pragma unroll
        for (int m = 0; m < 64; m++) {
            float pv = pl[row][m];
            float4 a = *(const float4*)&Vt[m][sub * 8];
            float4 b = *(const float4*)&Vt[m][sub * 8 + 4];
            daccA = f4fma(pv, a, daccA); daccB = f4fma(pv, b, daccB);
        }
        __syncthreads();
    }

    const float rinv = 1.0f / srun;
    float4 oA = f4scale(daccA, rinv), oB = f4scale(daccB, rinv);
    if (side == 0) {
        const float* vv = vin + (size_t)grow * 64 + sub * 8;
        oA = f4sub(oA, *(const float4*)vv);
        oB = f4sub(oB, *(const float4*)(vv + 4));
        float* dp = db + (size_t)grow * 64 + sub * 8;
        *(float4*)dp = oA; *(float4*)(dp + 4) = oB;
        if (sub == 0) { mfk[grow] = mrun; rsk[grow] = rinv; }
    } else {
        float* op = out + (size_t)grow * 64 + sub * 8;
        *(float4*)op = oA; *(float4*)(op + 4) = oB;
        if (sub == 0) { mfq[grow] = mrun; rsq[grow] = rinv; }
    }
}

// ---------------------------------------------------------------------------
// K2: G_c[m,dv] = sum_{t in chunk c} a_k[t,m]*d[t,dv], a_k recomputed.
// grid (M/64, NCH), 256 threads, tx=tid&15, ty=tid>>4.
// ---------------------------------------------------------------------------
__global__ __launch_bounds__(256) void k2_G(
    const float* __restrict__ kin, const float* __restrict__ Km,
    const float* __restrict__ mfk, const float* __restrict__ rsk,
    const float* __restrict__ db, float* __restrict__ Sb)
{
    __shared__ float Km2[64][66];   // K rows for this m-block
    __shared__ float ks[64][66];    // k rows (scaled); reused as p[t][m]
    __shared__ float ds[64][66];    // d rows
    const int c = blockIdx.y, mb = blockIdx.x * 64;
    const int tid = threadIdx.x, tx = tid & 15, ty = tid >> 4;

    {
        const int r = tid >> 2;
        #pragma unroll
        for (int qq = 0; qq < 4; qq++) {
            int c4 = (tid & 3) + qq * 4;
            *(float4*)&Km2[r][c4 * 4] =
                *(const float4*)(Km + (size_t)(mb + r) * 64 + c4 * 4);
        }
    }
    float4 accg[4] = { f4z(), f4z(), f4z(), f4z() };

    for (int tt = 0; tt < 4; tt++) {
        {
            const int r = tid >> 2;
            const int gt = c * CCH + tt * 64 + r;
            #pragma unroll
            for (int qq = 0; qq < 4; qq++) {
                int c4 = (tid & 3) + qq * 4;
                *(float4*)&ks[r][c4 * 4] =
                    f4scale(*(const float4*)(kin + (size_t)gt * 64 + c4 * 4), SCALE);
                *(float4*)&ds[r][c4 * 4] =
                    *(const float4*)(db + (size_t)gt * 64 + c4 * 4);
            }
        }
        __syncthreads();

        float s[4][4];
        #pragma unroll
        for (int a = 0; a < 4; a++)
            #pragma unroll
            for (int b = 0; b < 4; b++) s[a][b] = 0.f;
        #pragma unroll
        for (int kk4 = 0; kk4 < 16; kk4++) {
            float4 av[4], bv[4];
            #pragma unroll
            for (int a = 0; a < 4; a++) av[a] = *(const float4*)&ks[ty + 16 * a][kk4 * 4];
            #pragma unroll
            for (int b = 0; b < 4; b++) bv[b] = *(const float4*)&Km2[tx + 16 * b][kk4 * 4];
            #pragma unroll
            for (int a = 0; a < 4; a++)
                #pragma unroll
                for (int b = 0; b < 4; b++) s[a][b] += dot4(av[a], bv[b]);
        }
        __syncthreads();   // GEMM reads of ks done; reuse ks as p

        #pragma unroll
        for (int a = 0; a < 4; a++) {
            const int i = ty + 16 * a;
            const int gt = c * CCH + tt * 64 + i;
            const float mf = mfk[gt], rs = rsk[gt];
            #pragma unroll
            for (int b = 0; b < 4; b++)
                ks[i][tx + 16 * b] = __expf(s[a][b] - mf) * rs;
        }
        __syncthreads();

        #pragma unroll
        for (int t2 = 0; t2 < 64; t2++) {
            float4 d4 = *(const float4*)&ds[t2][tx * 4];
            #pragma unroll
            for (int a = 0; a < 4; a++)
                accg[a] = f4fma(ks[t2][ty + 16 * a], d4, accg[a]);
        }
        __syncthreads();
    }
    #pragma unroll
    for (int a = 0; a < 4; a++)
        *(float4*)(Sb + ((size_t)c * M_MEM + mb + ty + 16 * a) * 64 + tx * 4) = accg[a];
}

// ---------------------------------------------------------------------------
// K3: exclusive prefix over chunk axis: Sb[c] := sum_{c'<c} G[c']
// ---------------------------------------------------------------------------
__global__ __launch_bounds__(256) void k3_scan(float* __restrict__ Sb)
{
    const size_t idx = (size_t)blockIdx.x * 256 + threadIdx.x;
    float acc = 0.f;
    #pragma unroll
    for (int c = 0; c < NCH; c++) {
        float* p = Sb + (size_t)c * (M_MEM * DKV) + idx;
        float t = *p; *p = acc; acc += t;
    }
}

// ---------------------------------------------------------------------------
// K4: per chunk, 64x64 lower-tri tiles; recompute a_q/a_k logits in 32-wide
// m-tiles; out -= tril_strict(P)@d + (diag) a_q@S_c. grid (NCH*10), 256 thr.
// ---------------------------------------------------------------------------
__global__ __launch_bounds__(256) void k4_out(
    const float* __restrict__ qin, const float* __restrict__ kin,
    const float* __restrict__ Km,
    const float* __restrict__ mfq, const float* __restrict__ rsq,
    const float* __restrict__ mfk, const float* __restrict__ rsk,
    const float* __restrict__ Sb, const float* __restrict__ db,
    float* __restrict__ out)
{
    __shared__ float qr[64][66];   // q rows (scaled); later masked P
    __shared__ float kr[64][66];   // k rows (scaled); later d rows
    __shared__ float KS[32][66];   // K m-tile, re-staged as S_c m-tile (diag)
    __shared__ float pq[64][34];   // exp(sq - mq)
    __shared__ float pk[64][34];   // exp(sk - mk)

    const int rbA[10] = {0,1,1,2,2,2,3,3,3,3};
    const int cbA[10] = {0,0,1,0,1,2,0,1,2,3};
    const int c  = blockIdx.x / 10, t = blockIdx.x % 10;
    const int rb = rbA[t], cb = cbA[t];
    const bool diag = (rb == cb);
    const int rows_g = c * CCH + rb * 64, cols_g = c * CCH + cb * 64;
    const int tid = threadIdx.x, tx = tid & 15, ty = tid >> 4;

    {
        const int r = tid >> 2;
        #pragma unroll
        for (int qq = 0; qq < 4; qq++) {
            int c4 = (tid & 3) + qq * 4;
            *(float4*)&qr[r][c4 * 4] =
                f4scale(*(const float4*)(qin + (size_t)(rows_g + r) * 64 + c4 * 4), SCALE);
            *(float4*)&kr[r][c4 * 4] =
                f4scale(*(const float4*)(kin + (size_t)(cols_g + r) * 64 + c4 * 4), SCALE);
        }
    }
    float mq[4], mk[4], rqv[4];
    #pragma unroll
    for (int a = 0; a < 4; a++) {
        mq[a]  = mfq[rows_g + ty + 16 * a];
        mk[a]  = mfk[cols_g + ty + 16 * a];
        rqv[a] = rsq[rows_g + ty + 16 * a];
    }
    float rk_j[4];
    #pragma unroll
    for (int b = 0; b < 4; b++) rk_j[b] = rsk[cols_g + tx + 16 * b];

    float acc[4][4];
    #pragma unroll
    for (int a = 0; a < 4; a++)
        #pragma unroll
        for (int b = 0; b < 4; b++) acc[a][b] = 0.f;
    float4 racc[4] = { f4z(), f4z(), f4z(), f4z() };

    __syncthreads();

    for (int mt = 0; mt < 128; mt++) {
        const int m_base = mt * 32;
        {   // stage K m-tile
            const int r = tid >> 3, c8 = (tid & 7) * 8;
            const float* kp = Km + (size_t)(m_base + r) * 64 + c8;
            *(float4*)&KS[r][c8]     = *(const float4*)kp;
            *(float4*)&KS[r][c8 + 4] = *(const float4*)(kp + 4);
        }
        __syncthreads();

        float sq[4][2], sk[4][2];
        #pragma unroll
        for (int a = 0; a < 4; a++) { sq[a][0]=0.f; sq[a][1]=0.f; sk[a][0]=0.f; sk[a][1]=0.f; }
        #pragma unroll
        for (int kk4 = 0; kk4 < 16; kk4++) {
            float4 km0 = *(const float4*)&KS[tx][kk4 * 4];
            float4 km1 = *(const float4*)&KS[tx + 16][kk4 * 4];
            #pragma unroll
            for (int a = 0; a < 4; a++) {
                float4 qa = *(const float4*)&qr[ty + 16 * a][kk4 * 4];
                float4 ka = *(const float4*)&kr[ty + 16 * a][kk4 * 4];
                sq[a][0] += dot4(qa, km0); sq[a][1] += dot4(qa, km1);
                sk[a][0] += dot4(ka, km0); sk[a][1] += dot4(ka, km1);
            }
        }
        __syncthreads();   // KS reads done (diag re-stages it below)

        #pragma unroll
        for (int a = 0; a < 4; a++) {
            const int i = ty + 16 * a;
            pq[i][tx]      = __expf(sq[a][0] - mq[a]);
            pq[i][tx + 16] = __expf(sq[a][1] - mq[a]);
            pk[i][tx]      = __expf(sk[a][0] - mk[a]);
            pk[i][tx + 16] = __expf(sk[a][1] - mk[a]);
        }
        if (diag) {
            const int r = tid >> 3, c8 = (tid & 7) * 8;
            const float* sp = Sb + ((size_t)c * M_MEM + m_base + r) * 64 + c8;
            *(float4*)&KS[r][c8]     = *(const float4*)sp;
            *(float4*)&KS[r][c8 + 4] = *(const float4*)(sp + 4);
        }
        __syncthreads();

        #pragma unroll
        for (int m4 = 0; m4 < 8; m4++) {
            float4 qa[4], kb[4];
            #pragma unroll
            for (int a = 0; a < 4; a++) qa[a] = *(const float4*)&pq[ty + 16 * a][m4 * 4];
            #pragma unroll
            for (int b = 0; b < 4; b++) kb[b] = *(const float4*)&pk[tx + 16 * b][m4 * 4];
            #pragma unroll
            for (int a = 0; a < 4; a++)
                #pragma unroll
                for (int b = 0; b < 4; b++) acc[a][b] += dot4(qa[a], kb[b]);
        }
        if (diag) {
            #pragma unroll
            for (int m = 0; m < 32; m++) {
                float4 s4 = *(const float4*)&KS[m][tx * 4];
                #pragma unroll
                for (int a = 0; a < 4; a++)
                    racc[a] = f4fma(pq[ty + 16 * a][m], s4, racc[a]);
            }
        }
        __syncthreads();
    }

    // masked, normalized P -> qr; d rows -> kr
    #pragma unroll
    for (int a = 0; a < 4; a++)
        #pragma unroll
        for (int b = 0; b < 4; b++) {
            int i = ty + 16 * a, j = tx + 16 * b;
            float pv = ((cols_g + j) < (rows_g + i)) ? acc[a][b] * rqv[a] * rk_j[b] : 0.f;
            qr[i][j] = pv;
        }
    {
        const int r = tid >> 2;
        #pragma unroll
        for (int qq = 0; qq < 4; qq++) {
            int c4 = (tid & 3) + qq * 4;
            *(float4*)&kr[r][c4 * 4] =
                *(const float4*)(db + (size_t)(cols_g + r) * 64 + c4 * 4);
        }
    }
    __syncthreads();

    float4 res[4];
    #pragma unroll
    for (int a = 0; a < 4; a++)
        res[a] = diag ? f4scale(racc[a], rqv[a]) : f4z();
    #pragma unroll
    for (int j = 0; j < 64; j++) {
        float4 d4 = *(const float4*)&kr[j][tx * 4];
        #pragma unroll
        for (int a = 0; a < 4; a++)
            res[a] = f4fma(qr[ty + 16 * a][j], d4, res[a]);
    }
    #pragma unroll
    for (int a = 0; a < 4; a++) {
        float* op = out + (size_t)(rows_g + ty + 16 * a) * 64 + tx * 4;
        atomicAdd(op + 0, -res[a].x);
        atomicAdd(op + 1, -res[a].y);
        atomicAdd(op + 2, -res[a].z);
        atomicAdd(op + 3, -res[a].w);
    }
}

extern "C" void kernel_launch(void* const* d_in, const int* in_sizes, int n_in,
                              void* d_out, int out_size, void* d_ws, size_t ws_size,
                              hipStream_t stream)
{
    const float* q = (const float*)d_in[0];
    const float* k = (const float*)d_in[1];
    const float* v = (const float*)d_in[2];
    const float* K = (const float*)d_in[3];
    const float* V = (const float*)d_in[4];
    float* out = (float*)d_out;

    float* ws  = (float*)d_ws;
    float* Sb  = ws;                                   // NCH*M*DV   = 8,388,608
    float* db  = Sb + (size_t)NCH * M_MEM * DKV;       // T*DV       =   524,288
    float* mfk = db + (size_t)T_TOK * DKV;             // T
    float* rsk = mfk + T_TOK;                          // T
    float* mfq = rsk + T_TOK;                          // T
    float* rsq = mfq + T_TOK;                          // T
    // total 8,945,664 floats = 35.8 MB of ws

    k1_stats<<<dim3(T_TOK / 32, 2), 256, 0, stream>>>(
        k, q, K, V, v, mfk, rsk, mfq, rsq, db, out);
    k2_G<<<dim3(M_MEM / 64, NCH), 256, 0, stream>>>(k, K, mfk, rsk, db, Sb);
    k3_scan<<<dim3(M_MEM * DKV / 256), 256, 0, stream>>>(Sb);
    k4_out<<<dim3(NCH * 10), 256, 0, stream>>>(
        q, k, K, mfq, rsq, mfk, rsk, Sb, db, out);
}

// Round 5
// 1113.786 us; speedup vs baseline: 2.6072x; 2.6072x over previous
//
#include <hip/hip_runtime.h>
#include <hip/hip_bf16.h>
#include <math.h>

#define T_TOK 8192
#define M_MEM 4096
#define DKV 64
#define SCALE 0.125f
#define CCH 256
#define NCH (T_TOK / CCH)   // 32

typedef __attribute__((ext_vector_type(8))) short short8;
typedef __attribute__((ext_vector_type(4))) float f32x4;
typedef __attribute__((ext_vector_type(4))) unsigned short u16x4;
typedef __attribute__((ext_vector_type(8))) unsigned short u16x8;

#define MFMA(a, b, c) __builtin_amdgcn_mfma_f32_16x16x32_bf16((a), (b), (c), 0, 0, 0)

__device__ __forceinline__ float4 f4z() { return make_float4(0.f, 0.f, 0.f, 0.f); }
__device__ __forceinline__ float4 f4fma(float s, const float4 a, float4 c) {
    c.x = fmaf(s, a.x, c.x); c.y = fmaf(s, a.y, c.y);
    c.z = fmaf(s, a.z, c.z); c.w = fmaf(s, a.w, c.w); return c;
}
__device__ __forceinline__ float4 f4scale(const float4 a, float s) {
    return make_float4(a.x * s, a.y * s, a.z * s, a.w * s);
}
__device__ __forceinline__ float4 f4sub(const float4 a, const float4 b) {
    return make_float4(a.x - b.x, a.y - b.y, a.z - b.z, a.w - b.w);
}
__device__ __forceinline__ float4 f4exp(const float4 s, float mf, float sc) {
    return make_float4(__expf(s.x - mf) * sc, __expf(s.y - mf) * sc,
                       __expf(s.z - mf) * sc, __expf(s.w - mf) * sc);
}
__device__ __forceinline__ float dot4(const float4 a, const float4 b) {
    return a.x * b.x + a.y * b.y + a.z * b.z + a.w * b.w;
}

// float -> bf16 bits (RNE) and back
__device__ __forceinline__ unsigned short f2bf(float f) {
    unsigned int u = __float_as_uint(f);
    u += 0x7fffu + ((u >> 16) & 1u);
    return (unsigned short)(u >> 16);
}
__device__ __forceinline__ float bf2f(unsigned short h) {
    return __uint_as_float(((unsigned int)h) << 16);
}

// ---------------------------------------------------------------------------
// K0: split Km (fp32 [4096][64]) into bf16 hi/lo planes in ws.
// ---------------------------------------------------------------------------
__global__ __launch_bounds__(256) void k0_split(
    const float* __restrict__ Km,
    unsigned short* __restrict__ hi, unsigned short* __restrict__ lo)
{
    const int i = (blockIdx.x * 256 + threadIdx.x) * 4;   // 262144 elems total
    float4 f = *(const float4*)(Km + i);
    unsigned short h0 = f2bf(f.x), h1 = f2bf(f.y), h2 = f2bf(f.z), h3 = f2bf(f.w);
    unsigned short l0 = f2bf(f.x - bf2f(h0)), l1 = f2bf(f.y - bf2f(h1));
    unsigned short l2 = f2bf(f.z - bf2f(h2)), l3 = f2bf(f.w - bf2f(h3));
    u16x4 hv = {h0, h1, h2, h3}, lv = {l0, l1, l2, l3};
    *(u16x4*)(hi + i) = hv;
    *(u16x4*)(lo + i) = lv;
}

// ---------------------------------------------------------------------------
// K1: online softmax stats + a_x@V accumulation (unchanged from round 2).
// ---------------------------------------------------------------------------
__global__ __launch_bounds__(256) void k1_stats(
    const float* __restrict__ kin, const float* __restrict__ qin,
    const float* __restrict__ Km, const float* __restrict__ Vm,
    const float* __restrict__ vin,
    float* __restrict__ mfk, float* __restrict__ rsk,
    float* __restrict__ mfq, float* __restrict__ rsq,
    float* __restrict__ db, float* __restrict__ out)
{
    __shared__ float KtT[64][64];
    __shared__ float Vt[64][68];
    __shared__ float pl[32][65];

    const int tid = threadIdx.x;
    const int row = tid >> 3, sub = tid & 7;
    const int side = blockIdx.y;
    const int grow = blockIdx.x * 32 + row;
    const float* src = (side ? qin : kin);

    float4 kr4[16];
    {
        const float4* sr = (const float4*)(src + (size_t)grow * 64);
        #pragma unroll
        for (int i = 0; i < 16; i++) kr4[i] = f4scale(sr[i], SCALE);
    }

    float mrun = -INFINITY, srun = 0.f;
    float4 daccA = f4z(), daccB = f4z();

    for (int mt = 0; mt < 64; mt++) {
        {
            const int m = tid & 63;
            const int q0 = tid >> 6;
            #pragma unroll
            for (int q = 0; q < 4; q++) {
                int kk4 = q0 + q * 4;
                float4 f = *(const float4*)(Km + (size_t)(mt * 64 + m) * 64 + kk4 * 4);
                KtT[kk4 * 4 + 0][m] = f.x; KtT[kk4 * 4 + 1][m] = f.y;
                KtT[kk4 * 4 + 2][m] = f.z; KtT[kk4 * 4 + 3][m] = f.w;
            }
            const int m2 = tid >> 2;
            #pragma unroll
            for (int q = 0; q < 4; q++) {
                int c4 = (tid & 3) + q * 4;
                *(float4*)&Vt[m2][c4 * 4] =
                    *(const float4*)(Vm + (size_t)(mt * 64 + m2) * 64 + c4 * 4);
            }
        }
        __syncthreads();

        float4 sA = f4z(), sB = f4z();
        #pragma unroll
        for (int kk4 = 0; kk4 < 16; kk4++) {
            float4 kf = kr4[kk4];
            #pragma unroll
            for (int c = 0; c < 4; c++) {
                int kk = kk4 * 4 + c;
                float kv = (c == 0 ? kf.x : c == 1 ? kf.y : c == 2 ? kf.z : kf.w);
                float4 a = *(const float4*)&KtT[kk][sub * 8];
                float4 b = *(const float4*)&KtT[kk][sub * 8 + 4];
                sA = f4fma(kv, a, sA); sB = f4fma(kv, b, sB);
            }
        }
        float tmax = fmaxf(fmaxf(fmaxf(sA.x, sA.y), fmaxf(sA.z, sA.w)),
                           fmaxf(fmaxf(sB.x, sB.y), fmaxf(sB.z, sB.w)));
        #pragma unroll
        for (int o = 1; o < 8; o <<= 1) tmax = fmaxf(tmax, __shfl_xor(tmax, o, 8));
        float mnew = fmaxf(mrun, tmax);
        float corr = __expf(mrun - mnew);
        float4 pA = f4exp(sA, mnew, 1.f), pB = f4exp(sB, mnew, 1.f);
        float ts = pA.x + pA.y + pA.z + pA.w + pB.x + pB.y + pB.z + pB.w;
        #pragma unroll
        for (int o = 1; o < 8; o <<= 1) ts += __shfl_xor(ts, o, 8);
        srun = srun * corr + ts;
        mrun = mnew;
        daccA = f4scale(daccA, corr); daccB = f4scale(daccB, corr);
        pl[row][sub * 8 + 0] = pA.x; pl[row][sub * 8 + 1] = pA.y;
        pl[row][sub * 8 + 2] = pA.z; pl[row][sub * 8 + 3] = pA.w;
        pl[row][sub * 8 + 4] = pB.x; pl[row][sub * 8 + 5] = pB.y;
        pl[row][sub * 8 + 6] = pB.z; pl[row][sub * 8 + 7] = pB.w;
        __syncthreads();

        #pragma unroll
        for (int m = 0; m < 64; m++) {
            float pv = pl[row][m];
            float4 a = *(const float4*)&Vt[m][sub * 8];
            float4 b = *(const float4*)&Vt[m][sub * 8 + 4];
            daccA = f4fma(pv, a, daccA); daccB = f4fma(pv, b, daccB);
        }
        __syncthreads();
    }

    const float rinv = 1.0f / srun;
    float4 oA = f4scale(daccA, rinv), oB = f4scale(daccB, rinv);
    if (side == 0) {
        const float* vv = vin + (size_t)grow * 64 + sub * 8;
        oA = f4sub(oA, *(const float4*)vv);
        oB = f4sub(oB, *(const float4*)(vv + 4));
        float* dp = db + (size_t)grow * 64 + sub * 8;
        *(float4*)dp = oA; *(float4*)(dp + 4) = oB;
        if (sub == 0) { mfk[grow] = mrun; rsk[grow] = rinv; }
    } else {
        float* op = out + (size_t)grow * 64 + sub * 8;
        *(float4*)op = oA; *(float4*)(op + 4) = oB;
        if (sub == 0) { mfq[grow] = mrun; rsq[grow] = rinv; }
    }
}

// ---------------------------------------------------------------------------
// K2: G_c[m,dv] = sum_{t in chunk c} a_k[t,m]*d[t,dv] (unchanged round 2).
// ---------------------------------------------------------------------------
__global__ __launch_bounds__(256) void k2_G(
    const float* __restrict__ kin, const float* __restrict__ Km,
    const float* __restrict__ mfk, const float* __restrict__ rsk,
    const float* __restrict__ db, float* __restrict__ Sb)
{
    __shared__ float Km2[64][66];
    __shared__ float ks[64][66];
    __shared__ float ds[64][66];
    const int c = blockIdx.y, mb = blockIdx.x * 64;
    const int tid = threadIdx.x, tx = tid & 15, ty = tid >> 4;

    {
        const int r = tid >> 2;
        #pragma unroll
        for (int qq = 0; qq < 4; qq++) {
            int c4 = (tid & 3) + qq * 4;
            *(float4*)&Km2[r][c4 * 4] =
                *(const float4*)(Km + (size_t)(mb + r) * 64 + c4 * 4);
        }
    }
    float4 accg[4] = { f4z(), f4z(), f4z(), f4z() };

    for (int tt = 0; tt < 4; tt++) {
        {
            const int r = tid >> 2;
            const int gt = c * CCH + tt * 64 + r;
            #pragma unroll
            for (int qq = 0; qq < 4; qq++) {
                int c4 = (tid & 3) + qq * 4;
                *(float4*)&ks[r][c4 * 4] =
                    f4scale(*(const float4*)(kin + (size_t)gt * 64 + c4 * 4), SCALE);
                *(float4*)&ds[r][c4 * 4] =
                    *(const float4*)(db + (size_t)gt * 64 + c4 * 4);
            }
        }
        __syncthreads();

        float s[4][4];
        #pragma unroll
        for (int a = 0; a < 4; a++)
            #pragma unroll
            for (int b = 0; b < 4; b++) s[a][b] = 0.f;
        #pragma unroll
        for (int kk4 = 0; kk4 < 16; kk4++) {
            float4 av[4], bv[4];
            #pragma unroll
            for (int a = 0; a < 4; a++) av[a] = *(const float4*)&ks[ty + 16 * a][kk4 * 4];
            #pragma unroll
            for (int b = 0; b < 4; b++) bv[b] = *(const float4*)&Km2[tx + 16 * b][kk4 * 4];
            #pragma unroll
            for (int a = 0; a < 4; a++)
                #pragma unroll
                for (int b = 0; b < 4; b++) s[a][b] += dot4(av[a], bv[b]);
        }
        __syncthreads();

        #pragma unroll
        for (int a = 0; a < 4; a++) {
            const int i = ty + 16 * a;
            const int gt = c * CCH + tt * 64 + i;
            const float mf = mfk[gt], rs = rsk[gt];
            #pragma unroll
            for (int b = 0; b < 4; b++)
                ks[i][tx + 16 * b] = __expf(s[a][b] - mf) * rs;
        }
        __syncthreads();

        #pragma unroll
        for (int t2 = 0; t2 < 64; t2++) {
            float4 d4 = *(const float4*)&ds[t2][tx * 4];
            #pragma unroll
            for (int a = 0; a < 4; a++)
                accg[a] = f4fma(ks[t2][ty + 16 * a], d4, accg[a]);
        }
        __syncthreads();
    }
    #pragma unroll
    for (int a = 0; a < 4; a++)
        *(float4*)(Sb + ((size_t)c * M_MEM + mb + ty + 16 * a) * 64 + tx * 4) = accg[a];
}

// ---------------------------------------------------------------------------
// K3: exclusive prefix over chunk axis (unchanged).
// ---------------------------------------------------------------------------
__global__ __launch_bounds__(256) void k3_scan(float* __restrict__ Sb)
{
    const size_t idx = (size_t)blockIdx.x * 256 + threadIdx.x;
    float acc = 0.f;
    #pragma unroll
    for (int c = 0; c < NCH; c++) {
        float* p = Sb + (size_t)c * (M_MEM * DKV) + idx;
        float t = *p; *p = acc; acc += t;
    }
}

// ---------------------------------------------------------------------------
// K4 (MFMA): per chunk, 64x64 lower-tri tiles. Split-bf16 MFMA for:
//   Sq/Sk logits, P += Pq@Pk^T, racc^T += Sc^T@Pq^T (diag), res^T += dT@P^T.
// FIX vs round 3: racc (a_q@S_c part) must be scaled by rsq of its TOKEN
// (lane-indexed l15, D-layout col), which round 3 omitted -> absmax 46.9.
// grid (NCH*10), 256 threads = 4 waves; wave w owns token rows [16w,16w+16).
// ---------------------------------------------------------------------------
__global__ __launch_bounds__(256) void k4_mfma(
    const float* __restrict__ qin, const float* __restrict__ kin,
    const unsigned short* __restrict__ KmHiG, const unsigned short* __restrict__ KmLoG,
    const float* __restrict__ mfq, const float* __restrict__ rsq,
    const float* __restrict__ mfk, const float* __restrict__ rsk,
    const float* __restrict__ Sb, const float* __restrict__ db,
    float* __restrict__ out)
{
    __shared__ unsigned short KmHi[64][72], KmLo[64][72];
    __shared__ unsigned short PqHi[64][72], PqLo[64][72];   // reused as masked-P
    __shared__ unsigned short PkHi[64][72], PkLo[64][72];   // reused as dT
    __shared__ unsigned short ScHi[64][72], ScLo[64][72];   // diag only

    const int c = blockIdx.x / 10, t = blockIdx.x % 10;
    const int rb = (t >= 6) ? 3 : (t >= 3) ? 2 : (t >= 1) ? 1 : 0;
    const int cb = t - rb * (rb + 1) / 2;
    const bool diag = (rb == cb);
    const int rows_g = c * CCH + rb * 64, cols_g = c * CCH + cb * 64;
    const int tid = threadIdx.x;
    const int w = tid >> 6, lane = tid & 63;
    const int l15 = lane & 15, g = lane >> 4;

    // ---- per-lane A-frags for q and k rows (R_w = [16w,16w+16)), scaled ----
    short8 qAh[2], qAl[2], kAh[2], kAl[2];
    {
        const float* qp = qin + (size_t)(rows_g + 16 * w + l15) * 64 + 8 * g;
        const float* kp = kin + (size_t)(cols_g + 16 * w + l15) * 64 + 8 * g;
        #pragma unroll
        for (int ks = 0; ks < 2; ks++) {
            #pragma unroll
            for (int jj = 0; jj < 8; jj++) {
                float fq = qp[32 * ks + jj] * SCALE;
                unsigned short h = f2bf(fq);
                qAh[ks][jj] = (short)h;
                qAl[ks][jj] = (short)f2bf(fq - bf2f(h));
                float fk = kp[32 * ks + jj] * SCALE;
                unsigned short h2 = f2bf(fk);
                kAh[ks][jj] = (short)h2;
                kAl[ks][jj] = (short)f2bf(fk - bf2f(h2));
            }
        }
    }
    // ---- per-lane softmax stats ----
    float mqv[4], rqv[4], mkv[4], rkv[4];
    #pragma unroll
    for (int r = 0; r < 4; r++) {
        mqv[r] = mfq[rows_g + 16 * w + 4 * g + r];
        rqv[r] = rsq[rows_g + 16 * w + 4 * g + r];
        mkv[r] = mfk[cols_g + 16 * w + 4 * g + r];
    }
    #pragma unroll
    for (int f = 0; f < 4; f++) rkv[f] = rsk[cols_g + 16 * f + l15];
    const float rq_row = rsq[rows_g + 16 * w + l15];   // racc token norm (l15!)

    const f32x4 z = {0.f, 0.f, 0.f, 0.f};
    f32x4 pacc[4] = {z, z, z, z};
    f32x4 racc[4] = {z, z, z, z};

    const int sm = tid >> 2, sd0 = (tid & 3) * 16;   // staging coords

    for (int mt = 0; mt < 64; mt++) {
        const int mb = mt * 64;
        // ---- segment 1: stage Km hi/lo planes (pre-split by K0) ----
        {
            const unsigned short* hp = KmHiG + (size_t)(mb + sm) * 64 + sd0;
            const unsigned short* lp = KmLoG + (size_t)(mb + sm) * 64 + sd0;
            *(u16x8*)&KmHi[sm][sd0]     = *(const u16x8*)hp;
            *(u16x8*)&KmHi[sm][sd0 + 8] = *(const u16x8*)(hp + 8);
            *(u16x8*)&KmLo[sm][sd0]     = *(const u16x8*)lp;
            *(u16x8*)&KmLo[sm][sd0 + 8] = *(const u16x8*)(lp + 8);
        }
        __syncthreads();

        // ---- segment 2: Sq/Sk MFMA, exp, split-write Pq/Pk; diag: stage ScT ----
        f32x4 sq[4] = {z, z, z, z}, sk[4] = {z, z, z, z};
        #pragma unroll
        for (int f = 0; f < 4; f++) {
            #pragma unroll
            for (int ks = 0; ks < 2; ks++) {
                short8 bh = *(short8*)&KmHi[16 * f + l15][8 * g + 32 * ks];
                short8 bl = *(short8*)&KmLo[16 * f + l15][8 * g + 32 * ks];
                sq[f] = MFMA(qAh[ks], bh, sq[f]);
                sq[f] = MFMA(qAh[ks], bl, sq[f]);
                sq[f] = MFMA(qAl[ks], bh, sq[f]);
                sk[f] = MFMA(kAh[ks], bh, sk[f]);
                sk[f] = MFMA(kAh[ks], bl, sk[f]);
                sk[f] = MFMA(kAl[ks], bh, sk[f]);
            }
        }
        #pragma unroll
        for (int f = 0; f < 4; f++) {
            #pragma unroll
            for (int r = 0; r < 4; r++) {
                float pqv = __expf(sq[f][r] - mqv[r]);
                unsigned short h = f2bf(pqv);
                PqHi[16 * w + 4 * g + r][16 * f + l15] = h;
                PqLo[16 * w + 4 * g + r][16 * f + l15] = f2bf(pqv - bf2f(h));
                float pkv = __expf(sk[f][r] - mkv[r]);
                unsigned short h2 = f2bf(pkv);
                PkHi[16 * w + 4 * g + r][16 * f + l15] = h2;
                PkLo[16 * w + 4 * g + r][16 * f + l15] = f2bf(pkv - bf2f(h2));
            }
        }
        if (diag) {   // transpose+split Sc tile: ScT[dv][m]
            const float* sp = Sb + ((size_t)c * M_MEM + mb + sm) * 64 + sd0;
            float vals[16];
            *(float4*)&vals[0]  = *(const float4*)(sp + 0);
            *(float4*)&vals[4]  = *(const float4*)(sp + 4);
            *(float4*)&vals[8]  = *(const float4*)(sp + 8);
            *(float4*)&vals[12] = *(const float4*)(sp + 12);
            #pragma unroll
            for (int j = 0; j < 16; j++) {
                unsigned short h = f2bf(vals[j]);
                ScHi[sd0 + j][sm] = h;
                ScLo[sd0 + j][sm] = f2bf(vals[j] - bf2f(h));
            }
        }
        __syncthreads();

        // ---- segment 3: P-GEMM (+racc^T on diag) ----
        short8 pqh[2], pql[2];
        #pragma unroll
        for (int ks = 0; ks < 2; ks++) {
            pqh[ks] = *(short8*)&PqHi[16 * w + l15][8 * g + 32 * ks];
            pql[ks] = *(short8*)&PqLo[16 * w + l15][8 * g + 32 * ks];
        }
        #pragma unroll
        for (int f = 0; f < 4; f++) {
            #pragma unroll
            for (int ks = 0; ks < 2; ks++) {
                short8 bh = *(short8*)&PkHi[16 * f + l15][8 * g + 32 * ks];
                short8 bl = *(short8*)&PkLo[16 * f + l15][8 * g + 32 * ks];
                pacc[f] = MFMA(pqh[ks], bh, pacc[f]);
                pacc[f] = MFMA(pqh[ks], bl, pacc[f]);
                pacc[f] = MFMA(pql[ks], bh, pacc[f]);
            }
        }
        if (diag) {
            #pragma unroll
            for (int rf = 0; rf < 4; rf++) {
                #pragma unroll
                for (int ks = 0; ks < 2; ks++) {
                    short8 ah = *(short8*)&ScHi[16 * rf + l15][8 * g + 32 * ks];
                    short8 al = *(short8*)&ScLo[16 * rf + l15][8 * g + 32 * ks];
                    racc[rf] = MFMA(ah, pqh[ks], racc[rf]);
                    racc[rf] = MFMA(ah, pql[ks], racc[rf]);
                    racc[rf] = MFMA(al, pqh[ks], racc[rf]);
                }
            }
        }
        // no sync here: next-iter segment-1 writes only KmLds (last read
        // before this iteration's sync2); Pq/Pk writes of next iter are
        // after its sync1.
    }

    // ---- FIX: normalize the a_q@S_c part by this token's 1/sum BEFORE the
    //      (already-normalized) dT@P^T epilogue accumulates into racc. ----
    if (diag) {
        #pragma unroll
        for (int rf = 0; rf < 4; rf++)
            #pragma unroll
            for (int r = 0; r < 4; r++) racc[rf][r] *= rq_row;
    }
    __syncthreads();

    // ---- finalize: mask+normalize P -> Pq planes; stage dT -> Pk planes ----
    #pragma unroll
    for (int f = 0; f < 4; f++) {
        #pragma unroll
        for (int r = 0; r < 4; r++) {
            int ql_ = 16 * w + 4 * g + r, kl_ = 16 * f + l15;
            bool keep = (cols_g + kl_) < (rows_g + ql_);
            float pv = keep ? pacc[f][r] * rqv[r] * rkv[f] : 0.f;
            unsigned short h = f2bf(pv);
            PqHi[ql_][kl_] = h;
            PqLo[ql_][kl_] = f2bf(pv - bf2f(h));
        }
    }
    {   // dT[dv][k_tok] from db rows cols_g..cols_g+63
        const float* dp = db + (size_t)(cols_g + sm) * 64 + sd0;
        float vals[16];
        *(float4*)&vals[0]  = *(const float4*)(dp + 0);
        *(float4*)&vals[4]  = *(const float4*)(dp + 4);
        *(float4*)&vals[8]  = *(const float4*)(dp + 8);
        *(float4*)&vals[12] = *(const float4*)(dp + 12);
        #pragma unroll
        for (int j = 0; j < 16; j++) {
            unsigned short h = f2bf(vals[j]);
            PkHi[sd0 + j][sm] = h;
            PkLo[sd0 + j][sm] = f2bf(vals[j] - bf2f(h));
        }
    }
    __syncthreads();

    // ---- res^T = racc^T + dT @ P^T ----
    short8 pbh[2], pbl[2];
    #pragma unroll
    for (int ks = 0; ks < 2; ks++) {
        pbh[ks] = *(short8*)&PqHi[16 * w + l15][8 * g + 32 * ks];
        pbl[ks] = *(short8*)&PqLo[16 * w + l15][8 * g + 32 * ks];
    }
    #pragma unroll
    for (int rf = 0; rf < 4; rf++) {
        #pragma unroll
        for (int ks = 0; ks < 2; ks++) {
            short8 ah = *(short8*)&PkHi[16 * rf + l15][8 * g + 32 * ks];
            short8 al = *(short8*)&PkLo[16 * rf + l15][8 * g + 32 * ks];
            racc[rf] = MFMA(ah, pbh[ks], racc[rf]);
            racc[rf] = MFMA(ah, pbl[ks], racc[rf]);
            racc[rf] = MFMA(al, pbh[ks], racc[rf]);
        }
    }
    // ---- atomic subtract: element (dv = 16rf+4g+r, q = rows_g+16w+l15) ----
    {
        float* orow = out + (size_t)(rows_g + 16 * w + l15) * 64;
        #pragma unroll
        for (int rf = 0; rf < 4; rf++) {
            #pragma unroll
            for (int r = 0; r < 4; r++)
                atomicAdd(orow + 16 * rf + 4 * g + r, -racc[rf][r]);
        }
    }
}

extern "C" void kernel_launch(void* const* d_in, const int* in_sizes, int n_in,
                              void* d_out, int out_size, void* d_ws, size_t ws_size,
                              hipStream_t stream)
{
    const float* q = (const float*)d_in[0];
    const float* k = (const float*)d_in[1];
    const float* v = (const float*)d_in[2];
    const float* K = (const float*)d_in[3];
    const float* V = (const float*)d_in[4];
    float* out = (float*)d_out;

    float* ws  = (float*)d_ws;
    float* Sb  = ws;                                   // NCH*M*DV   = 8,388,608 f
    float* db  = Sb + (size_t)NCH * M_MEM * DKV;       // T*DV       =   524,288 f
    float* mfk = db + (size_t)T_TOK * DKV;             // T
    float* rsk = mfk + T_TOK;                          // T
    float* mfq = rsk + T_TOK;                          // T
    float* rsq = mfq + T_TOK;                          // T
    unsigned short* KmHiG = (unsigned short*)(rsq + T_TOK);   // 4096*64 u16
    unsigned short* KmLoG = KmHiG + (size_t)M_MEM * DKV;      // 4096*64 u16
    // total ~36.9 MB of ws

    k0_split<<<dim3(M_MEM * DKV / 1024), 256, 0, stream>>>(K, KmHiG, KmLoG);
    k1_stats<<<dim3(T_TOK / 32, 2), 256, 0, stream>>>(
        k, q, K, V, v, mfk, rsk, mfq, rsq, db, out);
    k2_G<<<dim3(M_MEM / 64, NCH), 256, 0, stream>>>(k, K, mfk, rsk, db, Sb);
    k3_scan<<<dim3(M_MEM * DKV / 256), 256, 0, stream>>>(Sb);
    k4_mfma<<<dim3(NCH * 10), 256, 0, stream>>>(
        q, k, KmHiG, KmLoG, mfq, rsq, mfk, rsk, Sb, db, out);
}

// Round 9
// 803.477 us; speedup vs baseline: 3.6142x; 1.3862x over previous
//
#include <hip/hip_runtime.h>
#include <hip/hip_bf16.h>
#include <math.h>

#define T_TOK 8192
#define M_MEM 4096
#define DKV 64
#define SCALE 0.125f
#define CCH 256
#define NCH (T_TOK / CCH)   // 32

typedef __attribute__((ext_vector_type(8))) short short8;
typedef __attribute__((ext_vector_type(4))) float f32x4;
typedef __attribute__((ext_vector_type(4))) unsigned short u16x4;
typedef __attribute__((ext_vector_type(8))) unsigned short u16x8;

#define MFMA(a, b, c) __builtin_amdgcn_mfma_f32_16x16x32_bf16((a), (b), (c), 0, 0, 0)

__device__ __forceinline__ float4 f4z() { return make_float4(0.f, 0.f, 0.f, 0.f); }
__device__ __forceinline__ float4 f4fma(float s, const float4 a, float4 c) {
    c.x = fmaf(s, a.x, c.x); c.y = fmaf(s, a.y, c.y);
    c.z = fmaf(s, a.z, c.z); c.w = fmaf(s, a.w, c.w); return c;
}
__device__ __forceinline__ float4 f4scale(const float4 a, float s) {
    return make_float4(a.x * s, a.y * s, a.z * s, a.w * s);
}
__device__ __forceinline__ float dot4(const float4 a, const float4 b) {
    return a.x * b.x + a.y * b.y + a.z * b.z + a.w * b.w;
}

// float -> bf16 bits (RNE) and back
__device__ __forceinline__ unsigned short f2bf(float f) {
    unsigned int u = __float_as_uint(f);
    u += 0x7fffu + ((u >> 16) & 1u);
    return (unsigned short)(u >> 16);
}
__device__ __forceinline__ float bf2f(unsigned short h) {
    return __uint_as_float(((unsigned int)h) << 16);
}

// ---------------------------------------------------------------------------
// K0: split Km (fp32 [4096][64]) into bf16 hi/lo planes in ws. (unchanged)
// ---------------------------------------------------------------------------
__global__ __launch_bounds__(256) void k0_split(
    const float* __restrict__ Km,
    unsigned short* __restrict__ hi, unsigned short* __restrict__ lo)
{
    const int i = (blockIdx.x * 256 + threadIdx.x) * 4;   // 262144 elems total
    float4 f = *(const float4*)(Km + i);
    unsigned short h0 = f2bf(f.x), h1 = f2bf(f.y), h2 = f2bf(f.z), h3 = f2bf(f.w);
    unsigned short l0 = f2bf(f.x - bf2f(h0)), l1 = f2bf(f.y - bf2f(h1));
    unsigned short l2 = f2bf(f.z - bf2f(h2)), l3 = f2bf(f.w - bf2f(h3));
    u16x4 hv = {h0, h1, h2, h3}, lv = {l0, l1, l2, l3};
    *(u16x4*)(hi + i) = hv;
    *(u16x4*)(lo + i) = lv;
}

// ---------------------------------------------------------------------------
// K0v: split + TRANSPOSE Vm (fp32 [4096][64]) -> VtHiG/VtLoG [64 dv][4096 m].
// 64 blocks x 256 threads; thread handles V[m][dv0..dv0+16).
// ---------------------------------------------------------------------------
__global__ __launch_bounds__(256) void k0v_splitT(
    const float* __restrict__ Vm,
    unsigned short* __restrict__ hiT, unsigned short* __restrict__ loT)
{
    const int m = blockIdx.x * 64 + (threadIdx.x >> 2);
    const int dv0 = (threadIdx.x & 3) * 16;
    float vals[16];
    const float* vp = Vm + (size_t)m * 64 + dv0;
    *(float4*)&vals[0]  = *(const float4*)(vp + 0);
    *(float4*)&vals[4]  = *(const float4*)(vp + 4);
    *(float4*)&vals[8]  = *(const float4*)(vp + 8);
    *(float4*)&vals[12] = *(const float4*)(vp + 12);
    #pragma unroll
    for (int j = 0; j < 16; j++) {
        unsigned short h = f2bf(vals[j]);
        hiT[(size_t)(dv0 + j) * M_MEM + m] = h;
        loT[(size_t)(dv0 + j) * M_MEM + m] = f2bf(vals[j] - bf2f(h));
    }
}

// ---------------------------------------------------------------------------
// K1 (MFMA): online-softmax stats + a_x@V via split-bf16 MFMA.
// Block = 64 tokens (4 waves x 16 rows), grid (T/64, 2 sides).
// Per m-tile: S = x@Km^T (MFMA, B from pre-split Km planes); online max/sum
// (D-layout rows = token 4g+r, cols = m 16f+l15; 16-lane butterfly);
// p split->LDS->A-frags; dacc += p@V (B from pre-split V^T planes).
// side 0 -> mfk,rsk, d=a_k@V-v; side 1 -> mfq,rsq, rq=a_q@V into out.
// ---------------------------------------------------------------------------
__global__ __launch_bounds__(256) void k1_mfma(
    const float* __restrict__ kin, const float* __restrict__ qin,
    const unsigned short* __restrict__ KmHiG, const unsigned short* __restrict__ KmLoG,
    const unsigned short* __restrict__ VtHiG, const unsigned short* __restrict__ VtLoG,
    const float* __restrict__ vin,
    float* __restrict__ mfk, float* __restrict__ rsk,
    float* __restrict__ mfq, float* __restrict__ rsq,
    float* __restrict__ db, float* __restrict__ out)
{
    __shared__ unsigned short KmHi[64][72], KmLo[64][72];
    __shared__ unsigned short VtHi[64][72], VtLo[64][72];
    __shared__ unsigned short PHi[64][72],  PLo[64][72];

    const int side = blockIdx.y;
    const int tb = blockIdx.x * 64;
    const int tid = threadIdx.x, w = tid >> 6, lane = tid & 63;
    const int l15 = lane & 15, g = lane >> 4;
    const float* src = side ? qin : kin;

    // A-frags for this wave's 16 token rows (row = l15, k = 8g+32ks+jj)
    short8 xAh[2], xAl[2];
    {
        const float* xp = src + (size_t)(tb + 16 * w + l15) * 64 + 8 * g;
        #pragma unroll
        for (int ks = 0; ks < 2; ks++) {
            #pragma unroll
            for (int jj = 0; jj < 8; jj++) {
                float fv = xp[32 * ks + jj] * SCALE;
                unsigned short h = f2bf(fv);
                xAh[ks][jj] = (short)h;
                xAl[ks][jj] = (short)f2bf(fv - bf2f(h));
            }
        }
    }

    float mrun[4], srun[4];
    #pragma unroll
    for (int r = 0; r < 4; r++) { mrun[r] = -INFINITY; srun[r] = 0.f; }
    const f32x4 z = {0.f, 0.f, 0.f, 0.f};
    f32x4 dacc[4] = {z, z, z, z};

    const int sm = tid >> 2, sd0 = (tid & 3) * 16;   // staging coords

    for (int mt = 0; mt < 64; mt++) {
        const int mb = mt * 64;
        {   // stage Km hi/lo tile (safe: prev logits done before prev sync2)
            const unsigned short* hp = KmHiG + (size_t)(mb + sm) * 64 + sd0;
            const unsigned short* lp = KmLoG + (size_t)(mb + sm) * 64 + sd0;
            *(u16x8*)&KmHi[sm][sd0]     = *(const u16x8*)hp;
            *(u16x8*)&KmHi[sm][sd0 + 8] = *(const u16x8*)(hp + 8);
            *(u16x8*)&KmLo[sm][sd0]     = *(const u16x8*)lp;
            *(u16x8*)&KmLo[sm][sd0 + 8] = *(const u16x8*)(lp + 8);
        }
        __syncthreads();   // sync1: Km ready; prev-iter PV (Vt readers) done
        {   // stage V^T hi/lo tile [dv][m]
            const unsigned short* hp = VtHiG + (size_t)sm * M_MEM + mb + sd0;
            const unsigned short* lp = VtLoG + (size_t)sm * M_MEM + mb + sd0;
            *(u16x8*)&VtHi[sm][sd0]     = *(const u16x8*)hp;
            *(u16x8*)&VtHi[sm][sd0 + 8] = *(const u16x8*)(hp + 8);
            *(u16x8*)&VtLo[sm][sd0]     = *(const u16x8*)lp;
            *(u16x8*)&VtLo[sm][sd0 + 8] = *(const u16x8*)(lp + 8);
        }

        // ---- logits S = x@Km^T (split-bf16, 3-term) ----
        f32x4 sq[4] = {z, z, z, z};
        #pragma unroll
        for (int f = 0; f < 4; f++) {
            #pragma unroll
            for (int ks = 0; ks < 2; ks++) {
                short8 bh = *(short8*)&KmHi[16 * f + l15][8 * g + 32 * ks];
                short8 bl = *(short8*)&KmLo[16 * f + l15][8 * g + 32 * ks];
                sq[f] = MFMA(xAh[ks], bh, sq[f]);
                sq[f] = MFMA(xAh[ks], bl, sq[f]);
                sq[f] = MFMA(xAl[ks], bh, sq[f]);
            }
        }

        // ---- online softmax over this tile's 64 m-cols ----
        float corr[4];
        #pragma unroll
        for (int r = 0; r < 4; r++) {
            float tm = fmaxf(fmaxf(sq[0][r], sq[1][r]), fmaxf(sq[2][r], sq[3][r]));
            #pragma unroll
            for (int o = 1; o < 16; o <<= 1) tm = fmaxf(tm, __shfl_xor(tm, o, 16));
            float mnew = fmaxf(mrun[r], tm);
            corr[r] = __expf(mrun[r] - mnew);
            mrun[r] = mnew;
        }
        float ts[4] = {0.f, 0.f, 0.f, 0.f};
        #pragma unroll
        for (int f = 0; f < 4; f++) {
            #pragma unroll
            for (int r = 0; r < 4; r++) {
                float pv = __expf(sq[f][r] - mrun[r]);
                ts[r] += pv;
                unsigned short h = f2bf(pv);
                PHi[16 * w + 4 * g + r][16 * f + l15] = h;
                PLo[16 * w + 4 * g + r][16 * f + l15] = f2bf(pv - bf2f(h));
            }
        }
        #pragma unroll
        for (int r = 0; r < 4; r++) {
            #pragma unroll
            for (int o = 1; o < 16; o <<= 1) ts[r] += __shfl_xor(ts[r], o, 16);
            srun[r] = srun[r] * corr[r] + ts[r];
        }
        #pragma unroll
        for (int f = 0; f < 4; f++)
            #pragma unroll
            for (int r = 0; r < 4; r++) dacc[f][r] *= corr[r];
        __syncthreads();   // sync2: P and Vt ready

        // ---- dacc += p @ V (split-bf16, 3-term) ----
        short8 pAh[2], pAl[2];
        #pragma unroll
        for (int ks = 0; ks < 2; ks++) {
            pAh[ks] = *(short8*)&PHi[16 * w + l15][8 * g + 32 * ks];
            pAl[ks] = *(short8*)&PLo[16 * w + l15][8 * g + 32 * ks];
        }
        #pragma unroll
        for (int f = 0; f < 4; f++) {
            #pragma unroll
            for (int ks = 0; ks < 2; ks++) {
                short8 bh = *(short8*)&VtHi[16 * f + l15][8 * g + 32 * ks];
                short8 bl = *(short8*)&VtLo[16 * f + l15][8 * g + 32 * ks];
                dacc[f] = MFMA(pAh[ks], bh, dacc[f]);
                dacc[f] = MFMA(pAh[ks], bl, dacc[f]);
                dacc[f] = MFMA(pAl[ks], bh, dacc[f]);
            }
        }
        // no end-of-loop sync: next sync1 orders next Vt-stage vs this PV,
        // and next Km-stage (pre-sync1) is ordered vs this logits by sync2.
    }

    // ---- epilogue: normalize, write stats + d/rq ----
    float rinv[4];
    #pragma unroll
    for (int r = 0; r < 4; r++) rinv[r] = 1.0f / srun[r];
    if (side == 0) {
        #pragma unroll
        for (int f = 0; f < 4; f++)
            #pragma unroll
            for (int r = 0; r < 4; r++) {
                int tok = tb + 16 * w + 4 * g + r;
                db[(size_t)tok * 64 + 16 * f + l15] =
                    dacc[f][r] * rinv[r] - vin[(size_t)tok * 64 + 16 * f + l15];
            }
        if (l15 == 0) {
            #pragma unroll
            for (int r = 0; r < 4; r++) {
                int tok = tb + 16 * w + 4 * g + r;
                mfk[tok] = mrun[r]; rsk[tok] = rinv[r];
            }
        }
    } else {
        #pragma unroll
        for (int f = 0; f < 4; f++)
            #pragma unroll
            for (int r = 0; r < 4; r++) {
                int tok = tb + 16 * w + 4 * g + r;
                out[(size_t)tok * 64 + 16 * f + l15] = dacc[f][r] * rinv[r];
            }
        if (l15 == 0) {
            #pragma unroll
            for (int r = 0; r < 4; r++) {
                int tok = tb + 16 * w + 4 * g + r;
                mfq[tok] = mrun[r]; rsq[tok] = rinv[r];
            }
        }
    }
}

// ---------------------------------------------------------------------------
// K2: G_c[m,dv] = sum_{t in chunk c} a_k[t,m]*d[t,dv] (unchanged, passing).
// ---------------------------------------------------------------------------
__global__ __launch_bounds__(256) void k2_G(
    const float* __restrict__ kin, const float* __restrict__ Km,
    const float* __restrict__ mfk, const float* __restrict__ rsk,
    const float* __restrict__ db, float* __restrict__ Sb)
{
    __shared__ float Km2[64][66];
    __shared__ float ks[64][66];
    __shared__ float ds[64][66];
    const int c = blockIdx.y, mb = blockIdx.x * 64;
    const int tid = threadIdx.x, tx = tid & 15, ty = tid >> 4;

    {
        const int r = tid >> 2;
        #pragma unroll
        for (int qq = 0; qq < 4; qq++) {
            int c4 = (tid & 3) + qq * 4;
            *(float4*)&Km2[r][c4 * 4] =
                *(const float4*)(Km + (size_t)(mb + r) * 64 + c4 * 4);
        }
    }
    float4 accg[4] = { f4z(), f4z(), f4z(), f4z() };

    for (int tt = 0; tt < 4; tt++) {
        {
            const int r = tid >> 2;
            const int gt = c * CCH + tt * 64 + r;
            #pragma unroll
            for (int qq = 0; qq < 4; qq++) {
                int c4 = (tid & 3) + qq * 4;
                *(float4*)&ks[r][c4 * 4] =
                    f4scale(*(const float4*)(kin + (size_t)gt * 64 + c4 * 4), SCALE);
                *(float4*)&ds[r][c4 * 4] =
                    *(const float4*)(db + (size_t)gt * 64 + c4 * 4);
            }
        }
        __syncthreads();

        float s[4][4];
        #pragma unroll
        for (int a = 0; a < 4; a++)
            #pragma unroll
            for (int b = 0; b < 4; b++) s[a][b] = 0.f;
        #pragma unroll
        for (int kk4 = 0; kk4 < 16; kk4++) {
            float4 av[4], bv[4];
            #pragma unroll
            for (int a = 0; a < 4; a++) av[a] = *(const float4*)&ks[ty + 16 * a][kk4 * 4];
            #pragma unroll
            for (int b = 0; b < 4; b++) bv[b] = *(const float4*)&Km2[tx + 16 * b][kk4 * 4];
            #pragma unroll
            for (int a = 0; a < 4; a++)
                #pragma unroll
                for (int b = 0; b < 4; b++) s[a][b] += dot4(av[a], bv[b]);
        }
        __syncthreads();

        #pragma unroll
        for (int a = 0; a < 4; a++) {
            const int i = ty + 16 * a;
            const int gt = c * CCH + tt * 64 + i;
            const float mf = mfk[gt], rs = rsk[gt];
            #pragma unroll
            for (int b = 0; b < 4; b++)
                ks[i][tx + 16 * b] = __expf(s[a][b] - mf) * rs;
        }
        __syncthreads();

        #pragma unroll
        for (int t2 = 0; t2 < 64; t2++) {
            float4 d4 = *(const float4*)&ds[t2][tx * 4];
            #pragma unroll
            for (int a = 0; a < 4; a++)
                accg[a] = f4fma(ks[t2][ty + 16 * a], d4, accg[a]);
        }
        __syncthreads();
    }
    #pragma unroll
    for (int a = 0; a < 4; a++)
        *(float4*)(Sb + ((size_t)c * M_MEM + mb + ty + 16 * a) * 64 + tx * 4) = accg[a];
}

// ---------------------------------------------------------------------------
// K3: exclusive prefix over chunk axis (unchanged).
// ---------------------------------------------------------------------------
__global__ __launch_bounds__(256) void k3_scan(float* __restrict__ Sb)
{
    const size_t idx = (size_t)blockIdx.x * 256 + threadIdx.x;
    float acc = 0.f;
    #pragma unroll
    for (int c = 0; c < NCH; c++) {
        float* p = Sb + (size_t)c * (M_MEM * DKV) + idx;
        float t = *p; *p = acc; acc += t;
    }
}

// ---------------------------------------------------------------------------
// K4 (MFMA): unchanged from round 5 (passing).
// ---------------------------------------------------------------------------
__global__ __launch_bounds__(256) void k4_mfma(
    const float* __restrict__ qin, const float* __restrict__ kin,
    const unsigned short* __restrict__ KmHiG, const unsigned short* __restrict__ KmLoG,
    const float* __restrict__ mfq, const float* __restrict__ rsq,
    const float* __restrict__ mfk, const float* __restrict__ rsk,
    const float* __restrict__ Sb, const float* __restrict__ db,
    float* __restrict__ out)
{
    __shared__ unsigned short KmHi[64][72], KmLo[64][72];
    __shared__ unsigned short PqHi[64][72], PqLo[64][72];   // reused as masked-P
    __shared__ unsigned short PkHi[64][72], PkLo[64][72];   // reused as dT
    __shared__ unsigned short ScHi[64][72], ScLo[64][72];   // diag only

    const int c = blockIdx.x / 10, t = blockIdx.x % 10;
    const int rb = (t >= 6) ? 3 : (t >= 3) ? 2 : (t >= 1) ? 1 : 0;
    const int cb = t - rb * (rb + 1) / 2;
    const bool diag = (rb == cb);
    const int rows_g = c * CCH + rb * 64, cols_g = c * CCH + cb * 64;
    const int tid = threadIdx.x;
    const int w = tid >> 6, lane = tid & 63;
    const int l15 = lane & 15, g = lane >> 4;

    short8 qAh[2], qAl[2], kAh[2], kAl[2];
    {
        const float* qp = qin + (size_t)(rows_g + 16 * w + l15) * 64 + 8 * g;
        const float* kp = kin + (size_t)(cols_g + 16 * w + l15) * 64 + 8 * g;
        #pragma unroll
        for (int ks = 0; ks < 2; ks++) {
            #pragma unroll
            for (int jj = 0; jj < 8; jj++) {
                float fq = qp[32 * ks + jj] * SCALE;
                unsigned short h = f2bf(fq);
                qAh[ks][jj] = (short)h;
                qAl[ks][jj] = (short)f2bf(fq - bf2f(h));
                float fk = kp[32 * ks + jj] * SCALE;
                unsigned short h2 = f2bf(fk);
                kAh[ks][jj] = (short)h2;
                kAl[ks][jj] = (short)f2bf(fk - bf2f(h2));
            }
        }
    }
    float mqv[4], rqv[4], mkv[4], rkv[4];
    #pragma unroll
    for (int r = 0; r < 4; r++) {
        mqv[r] = mfq[rows_g + 16 * w + 4 * g + r];
        rqv[r] = rsq[rows_g + 16 * w + 4 * g + r];
        mkv[r] = mfk[cols_g + 16 * w + 4 * g + r];
    }
    #pragma unroll
    for (int f = 0; f < 4; f++) rkv[f] = rsk[cols_g + 16 * f + l15];
    const float rq_row = rsq[rows_g + 16 * w + l15];   // racc token norm (l15!)

    const f32x4 z = {0.f, 0.f, 0.f, 0.f};
    f32x4 pacc[4] = {z, z, z, z};
    f32x4 racc[4] = {z, z, z, z};

    const int sm = tid >> 2, sd0 = (tid & 3) * 16;

    for (int mt = 0; mt < 64; mt++) {
        const int mb = mt * 64;
        {
            const unsigned short* hp = KmHiG + (size_t)(mb + sm) * 64 + sd0;
            const unsigned short* lp = KmLoG + (size_t)(mb + sm) * 64 + sd0;
            *(u16x8*)&KmHi[sm][sd0]     = *(const u16x8*)hp;
            *(u16x8*)&KmHi[sm][sd0 + 8] = *(const u16x8*)(hp + 8);
            *(u16x8*)&KmLo[sm][sd0]     = *(const u16x8*)lp;
            *(u16x8*)&KmLo[sm][sd0 + 8] = *(const u16x8*)(lp + 8);
        }
        __syncthreads();

        f32x4 sq[4] = {z, z, z, z}, sk[4] = {z, z, z, z};
        #pragma unroll
        for (int f = 0; f < 4; f++) {
            #pragma unroll
            for (int ks = 0; ks < 2; ks++) {
                short8 bh = *(short8*)&KmHi[16 * f + l15][8 * g + 32 * ks];
                short8 bl = *(short8*)&KmLo[16 * f + l15][8 * g + 32 * ks];
                sq[f] = MFMA(qAh[ks], bh, sq[f]);
                sq[f] = MFMA(qAh[ks], bl, sq[f]);
                sq[f] = MFMA(qAl[ks], bh, sq[f]);
                sk[f] = MFMA(kAh[ks], bh, sk[f]);
                sk[f] = MFMA(kAh[ks], bl, sk[f]);
                sk[f] = MFMA(kAl[ks], bh, sk[f]);
            }
        }
        #pragma unroll
        for (int f = 0; f < 4; f++) {
            #pragma unroll
            for (int r = 0; r < 4; r++) {
                float pqv = __expf(sq[f][r] - mqv[r]);
                unsigned short h = f2bf(pqv);
                PqHi[16 * w + 4 * g + r][16 * f + l15] = h;
                PqLo[16 * w + 4 * g + r][16 * f + l15] = f2bf(pqv - bf2f(h));
                float pkv = __expf(sk[f][r] - mkv[r]);
                unsigned short h2 = f2bf(pkv);
                PkHi[16 * w + 4 * g + r][16 * f + l15] = h2;
                PkLo[16 * w + 4 * g + r][16 * f + l15] = f2bf(pkv - bf2f(h2));
            }
        }
        if (diag) {
            const float* sp = Sb + ((size_t)c * M_MEM + mb + sm) * 64 + sd0;
            float vals[16];
            *(float4*)&vals[0]  = *(const float4*)(sp + 0);
            *(float4*)&vals[4]  = *(const float4*)(sp + 4);
            *(float4*)&vals[8]  = *(const float4*)(sp + 8);
            *(float4*)&vals[12] = *(const float4*)(sp + 12);
            #pragma unroll
            for (int j = 0; j < 16; j++) {
                unsigned short h = f2bf(vals[j]);
                ScHi[sd0 + j][sm] = h;
                ScLo[sd0 + j][sm] = f2bf(vals[j] - bf2f(h));
            }
        }
        __syncthreads();

        short8 pqh[2], pql[2];
        #pragma unroll
        for (int ks = 0; ks < 2; ks++) {
            pqh[ks] = *(short8*)&PqHi[16 * w + l15][8 * g + 32 * ks];
            pql[ks] = *(short8*)&PqLo[16 * w + l15][8 * g + 32 * ks];
        }
        #pragma unroll
        for (int f = 0; f < 4; f++) {
            #pragma unroll
            for (int ks = 0; ks < 2; ks++) {
                short8 bh = *(short8*)&PkHi[16 * f + l15][8 * g + 32 * ks];
                short8 bl = *(short8*)&PkLo[16 * f + l15][8 * g + 32 * ks];
                pacc[f] = MFMA(pqh[ks], bh, pacc[f]);
                pacc[f] = MFMA(pqh[ks], bl, pacc[f]);
                pacc[f] = MFMA(pql[ks], bh, pacc[f]);
            }
        }
        if (diag) {
            #pragma unroll
            for (int rf = 0; rf < 4; rf++) {
                #pragma unroll
                for (int ks = 0; ks < 2; ks++) {
                    short8 ah = *(short8*)&ScHi[16 * rf + l15][8 * g + 32 * ks];
                    short8 al = *(short8*)&ScLo[16 * rf + l15][8 * g + 32 * ks];
                    racc[rf] = MFMA(ah, pqh[ks], racc[rf]);
                    racc[rf] = MFMA(ah, pql[ks], racc[rf]);
                    racc[rf] = MFMA(al, pqh[ks], racc[rf]);
                }
            }
        }
    }

    if (diag) {
        #pragma unroll
        for (int rf = 0; rf < 4; rf++)
            #pragma unroll
            for (int r = 0; r < 4; r++) racc[rf][r] *= rq_row;
    }
    __syncthreads();

    #pragma unroll
    for (int f = 0; f < 4; f++) {
        #pragma unroll
        for (int r = 0; r < 4; r++) {
            int ql_ = 16 * w + 4 * g + r, kl_ = 16 * f + l15;
            bool keep = (cols_g + kl_) < (rows_g + ql_);
            float pv = keep ? pacc[f][r] * rqv[r] * rkv[f] : 0.f;
            unsigned short h = f2bf(pv);
            PqHi[ql_][kl_] = h;
            PqLo[ql_][kl_] = f2bf(pv - bf2f(h));
        }
    }
    {
        const float* dp = db + (size_t)(cols_g + sm) * 64 + sd0;
        float vals[16];
        *(float4*)&vals[0]  = *(const float4*)(dp + 0);
        *(float4*)&vals[4]  = *(const float4*)(dp + 4);
        *(float4*)&vals[8]  = *(const float4*)(dp + 8);
        *(float4*)&vals[12] = *(const float4*)(dp + 12);
        #pragma unroll
        for (int j = 0; j < 16; j++) {
            unsigned short h = f2bf(vals[j]);
            PkHi[sd0 + j][sm] = h;
            PkLo[sd0 + j][sm] = f2bf(vals[j] - bf2f(h));
        }
    }
    __syncthreads();

    short8 pbh[2], pbl[2];
    #pragma unroll
    for (int ks = 0; ks < 2; ks++) {
        pbh[ks] = *(short8*)&PqHi[16 * w + l15][8 * g + 32 * ks];
        pbl[ks] = *(short8*)&PqLo[16 * w + l15][8 * g + 32 * ks];
    }
    #pragma unroll
    for (int rf = 0; rf < 4; rf++) {
        #pragma unroll
        for (int ks = 0; ks < 2; ks++) {
            short8 ah = *(short8*)&PkHi[16 * rf + l15][8 * g + 32 * ks];
            short8 al = *(short8*)&PkLo[16 * rf + l15][8 * g + 32 * ks];
            racc[rf] = MFMA(ah, pbh[ks], racc[rf]);
            racc[rf] = MFMA(ah, pbl[ks], racc[rf]);
            racc[rf] = MFMA(al, pbh[ks], racc[rf]);
        }
    }
    {
        float* orow = out + (size_t)(rows_g + 16 * w + l15) * 64;
        #pragma unroll
        for (int rf = 0; rf < 4; rf++) {
            #pragma unroll
            for (int r = 0; r < 4; r++)
                atomicAdd(orow + 16 * rf + 4 * g + r, -racc[rf][r]);
        }
    }
}

extern "C" void kernel_launch(void* const* d_in, const int* in_sizes, int n_in,
                              void* d_out, int out_size, void* d_ws, size_t ws_size,
                              hipStream_t stream)
{
    const float* q = (const float*)d_in[0];
    const float* k = (const float*)d_in[1];
    const float* v = (const float*)d_in[2];
    const float* K = (const float*)d_in[3];
    const float* V = (const float*)d_in[4];
    float* out = (float*)d_out;

    float* ws  = (float*)d_ws;
    float* Sb  = ws;                                   // NCH*M*DV   = 8,388,608 f
    float* db  = Sb + (size_t)NCH * M_MEM * DKV;       // T*DV       =   524,288 f
    float* mfk = db + (size_t)T_TOK * DKV;             // T
    float* rsk = mfk + T_TOK;                          // T
    float* mfq = rsk + T_TOK;                          // T
    float* rsq = mfq + T_TOK;                          // T
    unsigned short* KmHiG = (unsigned short*)(rsq + T_TOK);   // 4096*64 u16
    unsigned short* KmLoG = KmHiG + (size_t)M_MEM * DKV;
    unsigned short* VtHiG = KmLoG + (size_t)M_MEM * DKV;      // [64][4096] u16
    unsigned short* VtLoG = VtHiG + (size_t)M_MEM * DKV;
    // total ~37.9 MB of ws

    k0_split<<<dim3(M_MEM * DKV / 1024), 256, 0, stream>>>(K, KmHiG, KmLoG);
    k0v_splitT<<<dim3(M_MEM / 64), 256, 0, stream>>>(V, VtHiG, VtLoG);
    k1_mfma<<<dim3(T_TOK / 64, 2), 256, 0, stream>>>(
        k, q, KmHiG, KmLoG, VtHiG, VtLoG, v, mfk, rsk, mfq, rsq, db, out);
    k2_G<<<dim3(M_MEM / 64, NCH), 256, 0, stream>>>(k, K, mfk, rsk, db, Sb);
    k3_scan<<<dim3(M_MEM * DKV / 256), 256, 0, stream>>>(Sb);
    k4_mfma<<<dim3(NCH * 10), 256, 0, stream>>>(
        q, k, KmHiG, KmLoG, mfq, rsq, mfk, rsk, Sb, db, out);
}